// Round 9
// baseline (411.316 us; speedup 1.0000x reference)
//
#include <hip/hip_runtime.h>
#include <hip/hip_bf16.h>

#define NN 3072
#define NWORD 96   // u32 mask words per row
#define HH 8

typedef short short8 __attribute__((ext_vector_type(8)));
typedef float float4v __attribute__((ext_vector_type(4)));
typedef unsigned short ushort4v __attribute__((ext_vector_type(4)));

__device__ __forceinline__ float bf2f(unsigned short u) {
  union { unsigned u; float f; } v; v.u = ((unsigned)u) << 16; return v.f;
}
__device__ __forceinline__ unsigned short f2bf(float f) {
  union { float f; unsigned u; } v; v.f = f;
  unsigned r = v.u + 0x7fffu + ((v.u >> 16) & 1u);
  return (unsigned short)(r >> 16);
}
// flag==1 -> buffers are bf16; flag==0 -> fp32
__device__ __forceinline__ float ldin(const void* p, size_t i, int isbf) {
  return isbf ? bf2f(((const unsigned short*)p)[i]) : ((const float*)p)[i];
}

// ---- dtype detect: adj is exactly {0.0,1.0}; fp32 words have low16==0 always ----
__global__ __launch_bounds__(256) void k_detect(const unsigned* __restrict__ aw,
                                                int* __restrict__ flag) {
  __shared__ int s;
  if (threadIdx.x == 0) s = 0;
  __syncthreads();
  int any = 0;
  for (int i = threadIdx.x; i < 16384; i += 256)
    any |= ((aw[i] & 0xFFFFu) != 0u);
  if (any) s = 1;   // benign race
  __syncthreads();
  if (threadIdx.x == 0) *flag = s;
}

// ---- build TRANSPOSED bitmask: maskT[word][row] ----
__global__ __launch_bounds__(256) void k_mask(const void* __restrict__ adj,
                                              const int* __restrict__ flag,
                                              unsigned* __restrict__ maskT) {
  int isbf = *flag;
  int row = blockIdx.y;
  int j = blockIdx.x * 256 + threadIdx.x;
  bool pred = ldin(adj, (size_t)row * NN + j, isbf) != 0.f;
  unsigned long long b = __ballot(pred);
  int lane = threadIdx.x & 63;
  int word = blockIdx.x * 8 + (threadIdx.x >> 6) * 2;   // 0..95 within row
  if (lane == 0) maskT[(size_t)word * NN + row] = (unsigned)b;
  else if (lane == 32) maskT[(size_t)(word + 1) * NN + row] = (unsigned)(b >> 32);
}

// ---- mergeState: h = x + (obs==1) * theta ----
__global__ __launch_bounds__(256) void k_merge(const void* __restrict__ x,
                                               const int* __restrict__ obs,
                                               const void* __restrict__ theta,
                                               const int* __restrict__ flag,
                                               unsigned short* __restrict__ h) {
  int isbf = *flag;
  int i = blockIdx.x * 256 + threadIdx.x;
  int row = i >> 8, c = i & 255;
  float v = ldin(x, i, isbf);
  if (obs[row] == 1) v += ldin(theta, c, isbf);
  h[i] = f2bf(v);
}

// ---- batched 16x16 LDS transpose: in[b][R][C] -> out[b][C][R] (out bf16) ----
__global__ __launch_bounds__(256) void k_transpose(const void* __restrict__ in,
                                                   const int* __restrict__ flag,
                                                   unsigned short* __restrict__ out,
                                                   int R, int C) {
  __shared__ __align__(16) unsigned short tile[16][17];
  int isbf = *flag;
  int b = blockIdx.z;
  size_t base = (size_t)b * R * C;
  unsigned short* pout = out + base;
  int r0 = blockIdx.y * 16, c0 = blockIdx.x * 16;
  int tc = threadIdx.x & 15, tr = threadIdx.x >> 4;
  tile[tr][tc] = f2bf(ldin(in, base + (size_t)(r0 + tr) * C + (c0 + tc), isbf));
  __syncthreads();
  pout[(size_t)(c0 + tr) * R + (r0 + tc)] = tile[tc][tr];
}

// ---- GEMM: CT[n][m] = sum_k A[m][k] * WT[n][k], all bf16, M=3072 ----
template<int K, int NCT, int ROWS>
__global__ __launch_bounds__(256) void k_gemm(const unsigned short* __restrict__ A,
                                              const unsigned short* __restrict__ WT,
                                              unsigned short* __restrict__ CT,
                                              long aOff, long wOff, long cOff) {
  constexpr int RT = ROWS / 16;
  int head = blockIdx.y;
  A += (size_t)head * aOff; WT += (size_t)head * wOff; CT += (size_t)head * cOff;
  int rowbase = blockIdx.x * ROWS;
  int t = threadIdx.x;
  int w = t >> 6, lane = t & 63;
  int q = lane >> 4, l = lane & 15;
  int colbase = w * 16 * NCT;
  float4v acc[RT][NCT];
#pragma unroll
  for (int rt = 0; rt < RT; rt++)
#pragma unroll
    for (int ct = 0; ct < NCT; ct++) { float4v z = {0.f, 0.f, 0.f, 0.f}; acc[rt][ct] = z; }

  for (int kb = 0; kb < K; kb += 32) {
    short8 af[RT], bfr[NCT];
#pragma unroll
    for (int rt = 0; rt < RT; rt++)
      af[rt] = *(const short8*)(A + (size_t)(rowbase + rt * 16 + l) * K + kb + q * 8);
#pragma unroll
    for (int ct = 0; ct < NCT; ct++)
      bfr[ct] = *(const short8*)(WT + (size_t)(colbase + ct * 16 + l) * K + kb + q * 8);
#pragma unroll
    for (int rt = 0; rt < RT; rt++)
#pragma unroll
      for (int ct = 0; ct < NCT; ct++)
        acc[rt][ct] = __builtin_amdgcn_mfma_f32_16x16x32_bf16(af[rt], bfr[ct], acc[rt][ct], 0, 0, 0);
  }
#pragma unroll
  for (int rt = 0; rt < RT; rt++)
#pragma unroll
    for (int ct = 0; ct < NCT; ct++) {
      int r = rowbase + rt * 16 + q * 4;          // C/D: row = quad*4 + reg
      int n = colbase + ct * 16 + l;              // C/D: col = lane&15
      ushort4v u;
      u.x = f2bf(acc[rt][ct].x); u.y = f2bf(acc[rt][ct].y);
      u.z = f2bf(acc[rt][ct].z); u.w = f2bf(acc[rt][ct].w);
      *(ushort4v*)(CT + (size_t)n * NN + r) = u;
    }
}

// ---- repack WhT (col-major [n][m]) into MFMA-B-fragment order:
//      chunk (head, jb32, ct16) = 64 lanes x 8 bf16 contiguous (1 KB) ----
template<int DCOL>
__global__ __launch_bounds__(256) void k_repack(const unsigned short* __restrict__ WhT,
                                                unsigned short* __restrict__ WhTf) {
  constexpr int CT = DCOL / 16;
  int chunk = blockIdx.x * 4 + (threadIdx.x >> 6);
  int lane = threadIdx.x & 63;
  int q = lane >> 4, l = lane & 15;
  int ct = chunk % CT;
  int jb = (chunk / CT) % (NN / 32);
  int head = chunk / (CT * (NN / 32));
  short8 v = *(const short8*)(WhT + (size_t)head * DCOL * NN
                              + (size_t)(ct * 16 + l) * NN + jb * 32 + q * 8);
  *(short8*)(WhTf + (size_t)chunk * 512 + lane * 8) = v;
}

// ---- out-layer GEMM, K split across blocks into fp32 partials ----
template<int K, int KS>
__global__ __launch_bounds__(256) void k_gemm_out(const unsigned short* __restrict__ A,
                                                  const unsigned short* __restrict__ WT,
                                                  float* __restrict__ gpart) {
  constexpr int KC = K / KS;
  int ks = blockIdx.y;
  int rowbase = blockIdx.x * 16;
  int t = threadIdx.x;
  int w = t >> 6, lane = t & 63;
  int q = lane >> 4, l = lane & 15;
  int colbase = w * 16;
  float4v acc = {0.f, 0.f, 0.f, 0.f};
  for (int kb = ks * KC; kb < ks * KC + KC; kb += 32) {
    short8 af = *(const short8*)(A + (size_t)(rowbase + l) * K + kb + q * 8);
    short8 bfr = *(const short8*)(WT + (size_t)(colbase + l) * K + kb + q * 8);
    acc = __builtin_amdgcn_mfma_f32_16x16x32_bf16(af, bfr, acc, 0, 0, 0);
  }
#pragma unroll
  for (int reg = 0; reg < 4; reg++) {
    int r = rowbase + q * 4 + reg;
    int n = colbase + l;
    gpart[((size_t)ks * 64 + n) * NN + r] = acc[reg];
  }
}

template<int KS>
__global__ __launch_bounds__(256) void k_gemm_red(const float* __restrict__ gpart,
                                                  unsigned short* __restrict__ WhoT) {
  int tid = blockIdx.x * 256 + threadIdx.x;   // over 64*NN
  int r = tid % NN, n = tid / NN;
  float s = 0.f;
#pragma unroll
  for (int ks = 0; ks < KS; ks++) s += gpart[((size_t)ks * 64 + n) * NN + r];
  WhoT[(size_t)n * NN + r] = f2bf(s);
}

// ---- f1/f2 GEMV from WhT: a-vec staged in LDS ----
template<int DC>
__global__ __launch_bounds__(256) void k_f12(const unsigned short* __restrict__ WhT,
                                             const void* __restrict__ avec,
                                             const int* __restrict__ flag,
                                             float* __restrict__ f1, float* __restrict__ f2) {
  __shared__ float as_[2 * DC];
  int isbf = *flag;
  int head = blockIdx.y;
  size_t abase = (size_t)head * 2 * DC;
  if (threadIdx.x < 2 * DC) as_[threadIdx.x] = ldin(avec, abase + threadIdx.x, isbf);
  __syncthreads();
  int r = blockIdx.x * 256 + threadIdx.x;
  const unsigned short* wt = WhT + (size_t)head * DC * NN;
  float s1 = 0.f, s2 = 0.f;
#pragma unroll 16
  for (int c = 0; c < DC; c++) {
    float wv = bf2f(wt[(size_t)c * NN + r]);
    s1 += wv * as_[c];
    s2 += wv * as_[DC + c];
  }
  f1[head * NN + r] = s1;
  f2[head * NN + r] = s2;
}

// ---- attention partial: barrier-free, LDS-free; full-DCOL waves (no exp
//      duplication), fragment-packed B, transposed mask, MFMA ones-column
//      denominator, head pinned to XCD via blockIdx.x % NH ----
// Block = 4 waves x 32 rows = 128 rows; all waves share B chunks (L1 reuse).
template<int DCOL, int S>
__global__ __launch_bounds__(256, 3) void k_attn_part(
    const unsigned* __restrict__ maskT,
    const float* __restrict__ f1g, const float* __restrict__ f2g,
    const unsigned short* __restrict__ WhTf,
    float* __restrict__ pnum, float* __restrict__ pden, int NH) {
  constexpr int NCT = DCOL / 16;
  constexpr int JCH = NN / S;
  int blk = blockIdx.x;
  int head = blk % NH;               // lowest bits -> XCD pin for NH=8
  int rest = blk / NH;
  int js = rest % S;
  int bx = rest / S;
  int w = threadIdx.x >> 6, lane = threadIdx.x & 63;
  int q = lane >> 4, l = lane & 15;
  int rowbase = bx * 128 + w * 32;
  const float* f2p = f2g + head * NN;
  size_t headJB = (size_t)head * (NN / 32);
  float f1c0 = f1g[head * NN + rowbase + l] * 1.44269504f;
  float f1c1 = f1g[head * NN + rowbase + 16 + l] * 1.44269504f;

  // all-ones B fragment for the denominator MFMA (row sums of P)
  short8 ones;
#pragma unroll
  for (int i = 0; i < 8; i++) ones[i] = (short)0x3F80;

  float4v acc[2][NCT];
#pragma unroll
  for (int rt = 0; rt < 2; rt++)
#pragma unroll
    for (int ct = 0; ct < NCT; ct++) { float4v z = {0.f, 0.f, 0.f, 0.f}; acc[rt][ct] = z; }
  float4v accd[2];
  accd[0] = float4v{0.f, 0.f, 0.f, 0.f};
  accd[1] = float4v{0.f, 0.f, 0.f, 0.f};

  int j0 = js * JCH;
  unsigned mw0 = maskT[(size_t)(j0 >> 5) * NN + rowbase + l];
  unsigned mw1 = maskT[(size_t)(j0 >> 5) * NN + rowbase + 16 + l];
  float4v fa = *(const float4v*)(f2p + j0 + q * 8);
  float4v fb = *(const float4v*)(f2p + j0 + q * 8 + 4);

  for (int jb = j0; jb < j0 + JCH; jb += 32) {
    unsigned mwc0 = mw0 >> (q * 8);
    unsigned mwc1 = mw1 >> (q * 8);
    float4v fac = fa, fbc = fb;
    int jn = (jb + 32 < j0 + JCH) ? jb + 32 : j0;
    mw0 = maskT[(size_t)(jn >> 5) * NN + rowbase + l];
    mw1 = maskT[(size_t)(jn >> 5) * NN + rowbase + 16 + l];
    fa = *(const float4v*)(f2p + jn + q * 8);
    fb = *(const float4v*)(f2p + jn + q * 8 + 4);
    const unsigned short* bbase =
        WhTf + (headJB + (jb >> 5)) * (NCT * 512) + lane * 8;
    short8 bfr[NCT];
#pragma unroll
    for (int ct = 0; ct < NCT; ct++)   // coalesced 1KB fragment loads
      bfr[ct] = *(const short8*)(bbase + ct * 512);

    float p0[8], p1[8];
#pragma unroll
    for (int i = 0; i < 8; i++) {
      float fv = (i < 4) ? fac[i] : fbc[i - 4];
      float t0 = fmaf(fv, 1.44269504f, f1c0);     // log2e * (f1+f2)
      t0 = fminf(fmaxf(t0, 0.2f * t0), 43.f);     // leaky+clamp (med3 form)
      t0 = (mwc0 & (1u << i)) ? t0 : -200.f;
      p0[i] = exp2f(t0);
      float t1 = fmaf(fv, 1.44269504f, f1c1);
      t1 = fminf(fmaxf(t1, 0.2f * t1), 43.f);
      t1 = (mwc1 & (1u << i)) ? t1 : -200.f;
      p1[i] = exp2f(t1);
    }
    union { __hip_bfloat162 b2[4]; short8 s8; } u0, u1;
#pragma unroll
    for (int k = 0; k < 4; k++) {
      u0.b2[k] = __float22bfloat162_rn({p0[2 * k], p0[2 * k + 1]});
      u1.b2[k] = __float22bfloat162_rn({p1[2 * k], p1[2 * k + 1]});
    }
    accd[0] = __builtin_amdgcn_mfma_f32_16x16x32_bf16(u0.s8, ones, accd[0], 0, 0, 0);
    accd[1] = __builtin_amdgcn_mfma_f32_16x16x32_bf16(u1.s8, ones, accd[1], 0, 0, 0);
#pragma unroll
    for (int ct = 0; ct < NCT; ct++) {
      acc[0][ct] = __builtin_amdgcn_mfma_f32_16x16x32_bf16(u0.s8, bfr[ct], acc[0][ct], 0, 0, 0);
      acc[1][ct] = __builtin_amdgcn_mfma_f32_16x16x32_bf16(u1.s8, bfr[ct], acc[1][ct], 0, 0, 0);
    }
  }

  size_t slab = (size_t)(js * NH + head);
  if (l == 0) {   // accd replicated across all 16 cols; lanes 0,16,32,48 write
#pragma unroll
    for (int rt = 0; rt < 2; rt++)
#pragma unroll
      for (int reg = 0; reg < 4; reg++)
        pden[slab * NN + rowbase + rt * 16 + q * 4 + reg] = accd[rt][reg];
  }
#pragma unroll
  for (int rt = 0; rt < 2; rt++)
#pragma unroll
    for (int ct = 0; ct < NCT; ct++)
#pragma unroll
      for (int reg = 0; reg < 4; reg++) {
        int row = rowbase + rt * 16 + q * 4 + reg;
        int col = ct * 16 + l;
        pnum[(slab * NN + row) * DCOL + col] = acc[rt][ct][reg];
      }
}

// ---- combine partials: divide, ELU, store in layer-specific layout ----
template<int DCOL, int S>
__global__ __launch_bounds__(256) void k_attn_reduce(
    const float* __restrict__ pnum, const float* __restrict__ pden,
    void* __restrict__ outg, long outHeadOff, int outRowStride, int NH,
    const int* __restrict__ flag, int finalOut) {
  int tid = blockIdx.x * 256 + threadIdx.x;
  int col = tid & (DCOL - 1);
  int row = (tid / DCOL) % NN;
  int h = tid / (DCOL * NN);
  float sn = 0.f, sd = 0.f;
#pragma unroll
  for (int js = 0; js < S; js++) {
    size_t slab = (size_t)(js * NH + h);
    sn += pnum[(slab * NN + row) * DCOL + col];
    sd += pden[slab * NN + row];
  }
  float v = sd > 0.f ? sn / sd : 0.f;
  v = v > 0.f ? v : expm1f(v);                    // ELU
  size_t idx = (size_t)h * outHeadOff + (size_t)row * outRowStride + col;
  if (finalOut && *flag == 0) ((float*)outg)[idx] = v;
  else ((unsigned short*)outg)[idx] = f2bf(v);
}

extern "C" void kernel_launch(void* const* d_in, const int* in_sizes, int n_in,
                              void* d_out, int out_size, void* d_ws, size_t ws_size,
                              hipStream_t stream) {
  const void* x     = d_in[0];
  const void* adj   = d_in[1];
  const int*  obs   = (const int*)d_in[2];
  // d_in[3] s_mat unused (method='base')
  const void* theta = d_in[4];
  const void* W0    = d_in[5];
  const void* a0    = d_in[6];
  const void* W1    = d_in[7];
  const void* a1    = d_in[8];
  const void* Wo    = d_in[9];
  const void* ao    = d_in[10];

  char* ws = (char*)d_ws;
  size_t off = 0;
  auto alloc = [&](size_t bytes) { void* p = ws + off; off += (bytes + 255) & ~(size_t)255; return p; };
  int*            flag  = (int*)alloc(4);
  unsigned*       maskT = (unsigned*)alloc((size_t)NN * NWORD * 4);
  unsigned short* h_bf  = (unsigned short*)alloc((size_t)NN * 256 * 2);
  unsigned short* WhT   = (unsigned short*)alloc((size_t)HH * 128 * NN * 2);
  unsigned short* WhTf  = (unsigned short*)alloc((size_t)HH * 128 * NN * 2);
  float*          f1    = (float*)alloc((size_t)HH * NN * 4);
  float*          f2    = (float*)alloc((size_t)HH * NN * 4);
  unsigned short* h0    = (unsigned short*)alloc((size_t)HH * NN * 128 * 2);
  unsigned short* hc    = (unsigned short*)alloc((size_t)NN * 1024 * 2);
  unsigned short* W0T   = (unsigned short*)alloc((size_t)HH * 128 * 256 * 2);
  unsigned short* W1T   = (unsigned short*)alloc((size_t)HH * 128 * 128 * 2);
  unsigned short* WoT   = (unsigned short*)alloc((size_t)64 * 1024 * 2);
  unsigned short* WhoT  = (unsigned short*)alloc((size_t)64 * NN * 2);
  unsigned short* WhoTf = (unsigned short*)alloc((size_t)64 * NN * 2);
  float*          fo1   = (float*)alloc((size_t)NN * 4);
  float*          fo2   = (float*)alloc((size_t)NN * 4);
  float*          gpart = (float*)alloc((size_t)4 * 64 * NN * 4);

  // partial buffers sized by split factor S, bounded by ws_size
  size_t fixedEnd = off;
  auto needBytes = [&](int s) {
    return fixedEnd + (size_t)s * HH * NN * 128 * 4
         + (size_t)((s * HH > 16) ? s * HH : 16) * NN * 4 + 8192;
  };
  int S = (needBytes(4) <= ws_size) ? 4 : (needBytes(2) <= ws_size) ? 2 : 1;
  float* pnum = (float*)alloc((size_t)S * HH * NN * 128 * 4);   // >= 16*NN*64*4 even at S=1
  float* pden = (float*)alloc((size_t)((S * HH > 16) ? S * HH : 16) * NN * 4);

  k_detect<<<1, 256, 0, stream>>>((const unsigned*)adj, flag);
  k_mask<<<dim3(12, NN), 256, 0, stream>>>(adj, flag, maskT);
  k_merge<<<dim3(NN), 256, 0, stream>>>(x, obs, theta, flag, h_bf);
  k_transpose<<<dim3(8, 16, HH), 256, 0, stream>>>(W0, flag, W0T, 256, 128);
  k_transpose<<<dim3(8, 8, HH), 256, 0, stream>>>(W1, flag, W1T, 128, 128);
  k_transpose<<<dim3(4, 64, 1), 256, 0, stream>>>(Wo, flag, WoT, 1024, 64);

  // ---- layer 0 ----
  k_gemm<256, 2, 32><<<dim3(NN / 32, HH), 256, 0, stream>>>(h_bf, W0T, WhT,
                                                            0, 128 * 256, (long)128 * NN);
  k_repack<128><<<HH * (NN / 32) * 8 / 4, 256, 0, stream>>>(WhT, WhTf);
  k_f12<128><<<dim3(NN / 256, HH), 256, 0, stream>>>(WhT, a0, flag, f1, f2);
  switch (S) {
    case 4:
      k_attn_part<128, 4><<<(NN / 128) * 4 * HH, 256, 0, stream>>>(maskT, f1, f2, WhTf, pnum, pden, HH);
      k_attn_reduce<128, 4><<<dim3(HH * NN * 128 / 256), 256, 0, stream>>>(pnum, pden, h0, (long)NN * 128, 128, HH, flag, 0);
      break;
    case 2:
      k_attn_part<128, 2><<<(NN / 128) * 2 * HH, 256, 0, stream>>>(maskT, f1, f2, WhTf, pnum, pden, HH);
      k_attn_reduce<128, 2><<<dim3(HH * NN * 128 / 256), 256, 0, stream>>>(pnum, pden, h0, (long)NN * 128, 128, HH, flag, 0);
      break;
    default:
      k_attn_part<128, 1><<<(NN / 128) * 1 * HH, 256, 0, stream>>>(maskT, f1, f2, WhTf, pnum, pden, HH);
      k_attn_reduce<128, 1><<<dim3(HH * NN * 128 / 256), 256, 0, stream>>>(pnum, pden, h0, (long)NN * 128, 128, HH, flag, 0);
  }
  // ---- layer 1 ----
  k_gemm<128, 2, 32><<<dim3(NN / 32, HH), 256, 0, stream>>>(h0, W1T, WhT,
                                                            (long)NN * 128, 128 * 128, (long)128 * NN);
  k_repack<128><<<HH * (NN / 32) * 8 / 4, 256, 0, stream>>>(WhT, WhTf);
  k_f12<128><<<dim3(NN / 256, HH), 256, 0, stream>>>(WhT, a1, flag, f1, f2);
  switch (S) {
    case 4:
      k_attn_part<128, 4><<<(NN / 128) * 4 * HH, 256, 0, stream>>>(maskT, f1, f2, WhTf, pnum, pden, HH);
      k_attn_reduce<128, 4><<<dim3(HH * NN * 128 / 256), 256, 0, stream>>>(pnum, pden, hc, 128, 1024, HH, flag, 0);
      break;
    case 2:
      k_attn_part<128, 2><<<(NN / 128) * 2 * HH, 256, 0, stream>>>(maskT, f1, f2, WhTf, pnum, pden, HH);
      k_attn_reduce<128, 2><<<dim3(HH * NN * 128 / 256), 256, 0, stream>>>(pnum, pden, hc, 128, 1024, HH, flag, 0);
      break;
    default:
      k_attn_part<128, 1><<<(NN / 128) * 1 * HH, 256, 0, stream>>>(maskT, f1, f2, WhTf, pnum, pden, HH);
      k_attn_reduce<128, 1><<<dim3(HH * NN * 128 / 256), 256, 0, stream>>>(pnum, pden, hc, 128, 1024, HH, flag, 0);
  }
  // ---- output layer ----
  k_gemm_out<1024, 4><<<dim3(NN / 16, 4), 256, 0, stream>>>(hc, WoT, gpart);
  k_gemm_red<4><<<dim3(64 * NN / 256), 256, 0, stream>>>(gpart, WhoT);
  k_repack<64><<<(NN / 32) * 4 / 4, 256, 0, stream>>>(WhoT, WhoTf);
  k_f12<64><<<dim3(NN / 256, 1), 256, 0, stream>>>(WhoT, ao, flag, fo1, fo2);
  k_attn_part<64, 16><<<(NN / 128) * 16, 256, 0, stream>>>(maskT, fo1, fo2, WhoTf, pnum, pden, 1);
  k_attn_reduce<64, 16><<<dim3(NN * 64 / 256), 256, 0, stream>>>(pnum, pden, d_out, 0, 64, 1, flag, 1);
}

// Round 10
// 387.356 us; speedup vs baseline: 1.0619x; 1.0619x over previous
//
#include <hip/hip_runtime.h>
#include <hip/hip_bf16.h>

#define NN 3072
#define NWORD 96   // u32 mask words per row
#define HH 8

typedef short short8 __attribute__((ext_vector_type(8)));
typedef float float4v __attribute__((ext_vector_type(4)));
typedef unsigned short ushort4v __attribute__((ext_vector_type(4)));

__device__ __forceinline__ float bf2f(unsigned short u) {
  union { unsigned u; float f; } v; v.u = ((unsigned)u) << 16; return v.f;
}
__device__ __forceinline__ unsigned short f2bf(float f) {
  union { float f; unsigned u; } v; v.f = f;
  unsigned r = v.u + 0x7fffu + ((v.u >> 16) & 1u);
  return (unsigned short)(r >> 16);
}
// flag==1 -> buffers are bf16; flag==0 -> fp32
__device__ __forceinline__ float ldin(const void* p, size_t i, int isbf) {
  return isbf ? bf2f(((const unsigned short*)p)[i]) : ((const float*)p)[i];
}

// ---- dtype detect: adj is exactly {0.0,1.0}; fp32 words have low16==0 always ----
__global__ __launch_bounds__(256) void k_detect(const unsigned* __restrict__ aw,
                                                int* __restrict__ flag) {
  __shared__ int s;
  if (threadIdx.x == 0) s = 0;
  __syncthreads();
  int any = 0;
  for (int i = threadIdx.x; i < 16384; i += 256)
    any |= ((aw[i] & 0xFFFFu) != 0u);
  if (any) s = 1;   // benign race
  __syncthreads();
  if (threadIdx.x == 0) *flag = s;
}

// ---- build TRANSPOSED bitmask: maskT[word][row] ----
__global__ __launch_bounds__(256) void k_mask(const void* __restrict__ adj,
                                              const int* __restrict__ flag,
                                              unsigned* __restrict__ maskT) {
  int isbf = *flag;
  int row = blockIdx.y;
  int j = blockIdx.x * 256 + threadIdx.x;
  bool pred = ldin(adj, (size_t)row * NN + j, isbf) != 0.f;
  unsigned long long b = __ballot(pred);
  int lane = threadIdx.x & 63;
  int word = blockIdx.x * 8 + (threadIdx.x >> 6) * 2;   // 0..95 within row
  if (lane == 0) maskT[(size_t)word * NN + row] = (unsigned)b;
  else if (lane == 32) maskT[(size_t)(word + 1) * NN + row] = (unsigned)(b >> 32);
}

// ---- mergeState: h = x + (obs==1) * theta ----
__global__ __launch_bounds__(256) void k_merge(const void* __restrict__ x,
                                               const int* __restrict__ obs,
                                               const void* __restrict__ theta,
                                               const int* __restrict__ flag,
                                               unsigned short* __restrict__ h) {
  int isbf = *flag;
  int i = blockIdx.x * 256 + threadIdx.x;
  int row = i >> 8, c = i & 255;
  float v = ldin(x, i, isbf);
  if (obs[row] == 1) v += ldin(theta, c, isbf);
  h[i] = f2bf(v);
}

// ---- batched 16x16 LDS transpose: in[b][R][C] -> out[b][C][R] (out bf16) ----
__global__ __launch_bounds__(256) void k_transpose(const void* __restrict__ in,
                                                   const int* __restrict__ flag,
                                                   unsigned short* __restrict__ out,
                                                   int R, int C) {
  __shared__ __align__(16) unsigned short tile[16][17];
  int isbf = *flag;
  int b = blockIdx.z;
  size_t base = (size_t)b * R * C;
  unsigned short* pout = out + base;
  int r0 = blockIdx.y * 16, c0 = blockIdx.x * 16;
  int tc = threadIdx.x & 15, tr = threadIdx.x >> 4;
  tile[tr][tc] = f2bf(ldin(in, base + (size_t)(r0 + tr) * C + (c0 + tc), isbf));
  __syncthreads();
  pout[(size_t)(c0 + tr) * R + (r0 + tc)] = tile[tc][tr];
}

// ---- GEMM: CT[n][m] = sum_k A[m][k] * WT[n][k], all bf16, M=3072 ----
template<int K, int NCT, int ROWS>
__global__ __launch_bounds__(256) void k_gemm(const unsigned short* __restrict__ A,
                                              const unsigned short* __restrict__ WT,
                                              unsigned short* __restrict__ CT,
                                              long aOff, long wOff, long cOff) {
  constexpr int RT = ROWS / 16;
  int head = blockIdx.y;
  A += (size_t)head * aOff; WT += (size_t)head * wOff; CT += (size_t)head * cOff;
  int rowbase = blockIdx.x * ROWS;
  int t = threadIdx.x;
  int w = t >> 6, lane = t & 63;
  int q = lane >> 4, l = lane & 15;
  int colbase = w * 16 * NCT;
  float4v acc[RT][NCT];
#pragma unroll
  for (int rt = 0; rt < RT; rt++)
#pragma unroll
    for (int ct = 0; ct < NCT; ct++) { float4v z = {0.f, 0.f, 0.f, 0.f}; acc[rt][ct] = z; }

  for (int kb = 0; kb < K; kb += 32) {
    short8 af[RT], bfr[NCT];
#pragma unroll
    for (int rt = 0; rt < RT; rt++)
      af[rt] = *(const short8*)(A + (size_t)(rowbase + rt * 16 + l) * K + kb + q * 8);
#pragma unroll
    for (int ct = 0; ct < NCT; ct++)
      bfr[ct] = *(const short8*)(WT + (size_t)(colbase + ct * 16 + l) * K + kb + q * 8);
#pragma unroll
    for (int rt = 0; rt < RT; rt++)
#pragma unroll
      for (int ct = 0; ct < NCT; ct++)
        acc[rt][ct] = __builtin_amdgcn_mfma_f32_16x16x32_bf16(af[rt], bfr[ct], acc[rt][ct], 0, 0, 0);
  }
#pragma unroll
  for (int rt = 0; rt < RT; rt++)
#pragma unroll
    for (int ct = 0; ct < NCT; ct++) {
      int r = rowbase + rt * 16 + q * 4;          // C/D: row = quad*4 + reg
      int n = colbase + ct * 16 + l;              // C/D: col = lane&15
      ushort4v u;
      u.x = f2bf(acc[rt][ct].x); u.y = f2bf(acc[rt][ct].y);
      u.z = f2bf(acc[rt][ct].z); u.w = f2bf(acc[rt][ct].w);
      *(ushort4v*)(CT + (size_t)n * NN + r) = u;
    }
}

// ---- repack WhT (col-major [n][m]) into MFMA-B-fragment order:
//      chunk (head, jb32, ct16) = 64 lanes x 8 bf16 contiguous (1 KB) ----
template<int DCOL>
__global__ __launch_bounds__(256) void k_repack(const unsigned short* __restrict__ WhT,
                                                unsigned short* __restrict__ WhTf) {
  constexpr int CT = DCOL / 16;
  int chunk = blockIdx.x * 4 + (threadIdx.x >> 6);
  int lane = threadIdx.x & 63;
  int q = lane >> 4, l = lane & 15;
  int ct = chunk % CT;
  int jb = (chunk / CT) % (NN / 32);
  int head = chunk / (CT * (NN / 32));
  short8 v = *(const short8*)(WhT + (size_t)head * DCOL * NN
                              + (size_t)(ct * 16 + l) * NN + jb * 32 + q * 8);
  *(short8*)(WhTf + (size_t)chunk * 512 + lane * 8) = v;
}

// ---- out-layer GEMM, K split across blocks into fp32 partials ----
template<int K, int KS>
__global__ __launch_bounds__(256) void k_gemm_out(const unsigned short* __restrict__ A,
                                                  const unsigned short* __restrict__ WT,
                                                  float* __restrict__ gpart) {
  constexpr int KC = K / KS;
  int ks = blockIdx.y;
  int rowbase = blockIdx.x * 16;
  int t = threadIdx.x;
  int w = t >> 6, lane = t & 63;
  int q = lane >> 4, l = lane & 15;
  int colbase = w * 16;
  float4v acc = {0.f, 0.f, 0.f, 0.f};
  for (int kb = ks * KC; kb < ks * KC + KC; kb += 32) {
    short8 af = *(const short8*)(A + (size_t)(rowbase + l) * K + kb + q * 8);
    short8 bfr = *(const short8*)(WT + (size_t)(colbase + l) * K + kb + q * 8);
    acc = __builtin_amdgcn_mfma_f32_16x16x32_bf16(af, bfr, acc, 0, 0, 0);
  }
#pragma unroll
  for (int reg = 0; reg < 4; reg++) {
    int r = rowbase + q * 4 + reg;
    int n = colbase + l;
    gpart[((size_t)ks * 64 + n) * NN + r] = acc[reg];
  }
}

template<int KS>
__global__ __launch_bounds__(256) void k_gemm_red(const float* __restrict__ gpart,
                                                  unsigned short* __restrict__ WhoT) {
  int tid = blockIdx.x * 256 + threadIdx.x;   // over 64*NN
  int r = tid % NN, n = tid / NN;
  float s = 0.f;
#pragma unroll
  for (int ks = 0; ks < KS; ks++) s += gpart[((size_t)ks * 64 + n) * NN + r];
  WhoT[(size_t)n * NN + r] = f2bf(s);
}

// ---- f1/f2 GEMV from WhT: a-vec staged in LDS ----
template<int DC>
__global__ __launch_bounds__(256) void k_f12(const unsigned short* __restrict__ WhT,
                                             const void* __restrict__ avec,
                                             const int* __restrict__ flag,
                                             float* __restrict__ f1, float* __restrict__ f2) {
  __shared__ float as_[2 * DC];
  int isbf = *flag;
  int head = blockIdx.y;
  size_t abase = (size_t)head * 2 * DC;
  if (threadIdx.x < 2 * DC) as_[threadIdx.x] = ldin(avec, abase + threadIdx.x, isbf);
  __syncthreads();
  int r = blockIdx.x * 256 + threadIdx.x;
  const unsigned short* wt = WhT + (size_t)head * DC * NN;
  float s1 = 0.f, s2 = 0.f;
#pragma unroll 16
  for (int c = 0; c < DC; c++) {
    float wv = bf2f(wt[(size_t)c * NN + r]);
    s1 += wv * as_[c];
    s2 += wv * as_[DC + c];
  }
  f1[head * NN + r] = s1;
  f2[head * NN + r] = s2;
}

// ---- attention partial: barrier-free, LDS-free; full-DCOL waves (no exp
//      duplication), S j-chunks for parallelism, fragment-packed B,
//      transposed mask, ones-MFMA denominator, bf16 frag-order partials,
//      head pinned to XCD via blockIdx.x % NH ----
template<int DCOL, int S>
__global__ __launch_bounds__(256, 4) void k_attn_part(
    const unsigned* __restrict__ maskT,
    const float* __restrict__ f1g, const float* __restrict__ f2g,
    const unsigned short* __restrict__ WhTf,
    unsigned short* __restrict__ pnum, float* __restrict__ pden, int NH) {
  constexpr int NCT = DCOL / 16;
  constexpr int JCH = NN / S;
  int blk = blockIdx.x;
  int head = blk % NH;               // lowest bits -> XCD pin for NH=8
  int rest = blk / NH;
  int js = rest % S;
  int bx = rest / S;
  int w = threadIdx.x >> 6, lane = threadIdx.x & 63;
  int q = lane >> 4, l = lane & 15;
  int rowbase = bx * 128 + w * 32;
  const float* f2p = f2g + head * NN;
  size_t headJB = (size_t)head * (NN / 32);
  float f1c0 = f1g[head * NN + rowbase + l] * 1.44269504f;
  float f1c1 = f1g[head * NN + rowbase + 16 + l] * 1.44269504f;

  // all-ones B fragment for the denominator MFMA (row sums of P)
  short8 ones;
#pragma unroll
  for (int i = 0; i < 8; i++) ones[i] = (short)0x3F80;

  float4v acc[2][NCT];
#pragma unroll
  for (int rt = 0; rt < 2; rt++)
#pragma unroll
    for (int ct = 0; ct < NCT; ct++) { float4v z = {0.f, 0.f, 0.f, 0.f}; acc[rt][ct] = z; }
  float4v accd[2];
  accd[0] = float4v{0.f, 0.f, 0.f, 0.f};
  accd[1] = float4v{0.f, 0.f, 0.f, 0.f};

  int j0 = js * JCH;
  unsigned mw0 = maskT[(size_t)(j0 >> 5) * NN + rowbase + l];
  unsigned mw1 = maskT[(size_t)(j0 >> 5) * NN + rowbase + 16 + l];
  float4v fa = *(const float4v*)(f2p + j0 + q * 8);
  float4v fb = *(const float4v*)(f2p + j0 + q * 8 + 4);

  for (int jb = j0; jb < j0 + JCH; jb += 32) {
    unsigned mwc0 = mw0 >> (q * 8);
    unsigned mwc1 = mw1 >> (q * 8);
    float4v fac = fa, fbc = fb;
    int jn = (jb + 32 < j0 + JCH) ? jb + 32 : j0;
    mw0 = maskT[(size_t)(jn >> 5) * NN + rowbase + l];
    mw1 = maskT[(size_t)(jn >> 5) * NN + rowbase + 16 + l];
    fa = *(const float4v*)(f2p + jn + q * 8);
    fb = *(const float4v*)(f2p + jn + q * 8 + 4);
    const unsigned short* bbase =
        WhTf + (headJB + (jb >> 5)) * (NCT * 512) + lane * 8;
    short8 bfr[NCT];
#pragma unroll
    for (int ct = 0; ct < NCT; ct++)   // coalesced 1KB fragment loads
      bfr[ct] = *(const short8*)(bbase + ct * 512);

    float p0[8], p1[8];
#pragma unroll
    for (int i = 0; i < 8; i++) {
      float fv = (i < 4) ? fac[i] : fbc[i - 4];
      float t0 = fmaf(fv, 1.44269504f, f1c0);               // log2e*(f1+f2)
      t0 = __builtin_amdgcn_fmed3f(t0, 0.2f * t0, 43.f);    // leaky+clamp
      t0 = (mwc0 & (1u << i)) ? t0 : -200.f;
      p0[i] = exp2f(t0);
      float t1 = fmaf(fv, 1.44269504f, f1c1);
      t1 = __builtin_amdgcn_fmed3f(t1, 0.2f * t1, 43.f);
      t1 = (mwc1 & (1u << i)) ? t1 : -200.f;
      p1[i] = exp2f(t1);
    }
    union { __hip_bfloat162 b2[4]; short8 s8; } u0, u1;
#pragma unroll
    for (int k = 0; k < 4; k++) {
      u0.b2[k] = __float22bfloat162_rn({p0[2 * k], p0[2 * k + 1]});
      u1.b2[k] = __float22bfloat162_rn({p1[2 * k], p1[2 * k + 1]});
    }
    accd[0] = __builtin_amdgcn_mfma_f32_16x16x32_bf16(u0.s8, ones, accd[0], 0, 0, 0);
    accd[1] = __builtin_amdgcn_mfma_f32_16x16x32_bf16(u1.s8, ones, accd[1], 0, 0, 0);
#pragma unroll
    for (int ct = 0; ct < NCT; ct++) {
      acc[0][ct] = __builtin_amdgcn_mfma_f32_16x16x32_bf16(u0.s8, bfr[ct], acc[0][ct], 0, 0, 0);
      acc[1][ct] = __builtin_amdgcn_mfma_f32_16x16x32_bf16(u1.s8, bfr[ct], acc[1][ct], 0, 0, 0);
    }
  }

  size_t slab = (size_t)(js * NH + head);
  if (l == 0) {   // accd replicated across cols; lanes 0,16,32,48 cover rows
#pragma unroll
    for (int rt = 0; rt < 2; rt++)
#pragma unroll
      for (int reg = 0; reg < 4; reg++)
        pden[slab * NN + rowbase + rt * 16 + q * 4 + reg] = accd[rt][reg];
  }
  // numerator: bf16, MFMA-fragment order -> fully coalesced 512B stores
  int trb = rowbase >> 4;              // global 16-row tile index
#pragma unroll
  for (int rt = 0; rt < 2; rt++)
#pragma unroll
    for (int ct = 0; ct < NCT; ct++) {
      ushort4v u;
      u.x = f2bf(acc[rt][ct].x); u.y = f2bf(acc[rt][ct].y);
      u.z = f2bf(acc[rt][ct].z); u.w = f2bf(acc[rt][ct].w);
      size_t cidx = ((slab * (NN / 16) + trb + rt) * NCT + ct) * 256 + lane * 4;
      *(ushort4v*)(pnum + cidx) = u;
    }
}

// ---- combine partials (bf16 frag-order): divide, ELU, store layer layout ----
template<int DCOL, int S>
__global__ __launch_bounds__(256) void k_attn_reduce(
    const unsigned short* __restrict__ pnum, const float* __restrict__ pden,
    void* __restrict__ outg, long outHeadOff, int outRowStride, int NH,
    const int* __restrict__ flag, int finalOut) {
  constexpr int NCT = DCOL / 16;
  int tid = blockIdx.x * 256 + threadIdx.x;   // over NH*NN*DCOL
  int h = tid / (NN * DCOL);
  int e = tid % (NN * DCOL);
  int tile = e >> 8, r4 = e & 255;
  int ct = tile % NCT, tr = tile / NCT;
  int lane = r4 >> 2, reg = r4 & 3;
  int q = lane >> 4, l = lane & 15;
  int row = tr * 16 + q * 4 + reg;
  int col = ct * 16 + l;
  float sn = 0.f, sd = 0.f;
#pragma unroll
  for (int js = 0; js < S; js++) {
    size_t sl = (size_t)(js * NH + h);
    sn += bf2f(pnum[sl * (size_t)(NN * DCOL) + e]);   // coalesced
    sd += pden[sl * NN + row];
  }
  float v = sd > 0.f ? sn / sd : 0.f;
  v = v > 0.f ? v : expm1f(v);                    // ELU
  size_t idx = (size_t)h * outHeadOff + (size_t)row * outRowStride + col;
  if (finalOut && *flag == 0) ((float*)outg)[idx] = v;
  else ((unsigned short*)outg)[idx] = f2bf(v);
}

extern "C" void kernel_launch(void* const* d_in, const int* in_sizes, int n_in,
                              void* d_out, int out_size, void* d_ws, size_t ws_size,
                              hipStream_t stream) {
  const void* x     = d_in[0];
  const void* adj   = d_in[1];
  const int*  obs   = (const int*)d_in[2];
  // d_in[3] s_mat unused (method='base')
  const void* theta = d_in[4];
  const void* W0    = d_in[5];
  const void* a0    = d_in[6];
  const void* W1    = d_in[7];
  const void* a1    = d_in[8];
  const void* Wo    = d_in[9];
  const void* ao    = d_in[10];

  char* ws = (char*)d_ws;
  size_t off = 0;
  auto alloc = [&](size_t bytes) { void* p = ws + off; off += (bytes + 255) & ~(size_t)255; return p; };
  int*            flag  = (int*)alloc(4);
  unsigned*       maskT = (unsigned*)alloc((size_t)NN * NWORD * 4);
  unsigned short* h_bf  = (unsigned short*)alloc((size_t)NN * 256 * 2);
  unsigned short* WhT   = (unsigned short*)alloc((size_t)HH * 128 * NN * 2);
  unsigned short* WhTf  = (unsigned short*)alloc((size_t)HH * 128 * NN * 2);
  float*          f1    = (float*)alloc((size_t)HH * NN * 4);
  float*          f2    = (float*)alloc((size_t)HH * NN * 4);
  unsigned short* h0    = (unsigned short*)alloc((size_t)HH * NN * 128 * 2);
  unsigned short* hc    = (unsigned short*)alloc((size_t)NN * 1024 * 2);
  unsigned short* W0T   = (unsigned short*)alloc((size_t)HH * 128 * 256 * 2);
  unsigned short* W1T   = (unsigned short*)alloc((size_t)HH * 128 * 128 * 2);
  unsigned short* WoT   = (unsigned short*)alloc((size_t)64 * 1024 * 2);
  unsigned short* WhoT  = (unsigned short*)alloc((size_t)64 * NN * 2);
  unsigned short* WhoTf = (unsigned short*)alloc((size_t)64 * NN * 2);
  float*          fo1   = (float*)alloc((size_t)NN * 4);
  float*          fo2   = (float*)alloc((size_t)NN * 4);
  float*          gpart = (float*)alloc((size_t)4 * 64 * NN * 4);

  // partial buffers: bf16 numerators (frag order) + fp32 denominators
  size_t fixedEnd = off;
  auto needBytes = [&](int s) {
    size_t slabs = (size_t)((s * HH > 32) ? s * HH : 32);
    return fixedEnd + (size_t)s * HH * NN * 128 * 2 + slabs * NN * 4 + 8192;
  };
  int S = (needBytes(8) <= ws_size) ? 8 : (needBytes(4) <= ws_size) ? 4 : 2;
  unsigned short* pnum = (unsigned short*)alloc((size_t)S * HH * NN * 128 * 2);
  float* pden = (float*)alloc((size_t)((S * HH > 32) ? S * HH : 32) * NN * 4);

  k_detect<<<1, 256, 0, stream>>>((const unsigned*)adj, flag);
  k_mask<<<dim3(12, NN), 256, 0, stream>>>(adj, flag, maskT);
  k_merge<<<dim3(NN), 256, 0, stream>>>(x, obs, theta, flag, h_bf);
  k_transpose<<<dim3(8, 16, HH), 256, 0, stream>>>(W0, flag, W0T, 256, 128);
  k_transpose<<<dim3(8, 8, HH), 256, 0, stream>>>(W1, flag, W1T, 128, 128);
  k_transpose<<<dim3(4, 64, 1), 256, 0, stream>>>(Wo, flag, WoT, 1024, 64);

  // ---- layer 0 ----
  k_gemm<256, 2, 32><<<dim3(NN / 32, HH), 256, 0, stream>>>(h_bf, W0T, WhT,
                                                            0, 128 * 256, (long)128 * NN);
  k_repack<128><<<HH * (NN / 32) * 8 / 4, 256, 0, stream>>>(WhT, WhTf);
  k_f12<128><<<dim3(NN / 256, HH), 256, 0, stream>>>(WhT, a0, flag, f1, f2);
  switch (S) {
    case 8:
      k_attn_part<128, 8><<<(NN / 128) * 8 * HH, 256, 0, stream>>>(maskT, f1, f2, WhTf, pnum, pden, HH);
      k_attn_reduce<128, 8><<<HH * NN * 128 / 256, 256, 0, stream>>>(pnum, pden, h0, (long)NN * 128, 128, HH, flag, 0);
      break;
    case 4:
      k_attn_part<128, 4><<<(NN / 128) * 4 * HH, 256, 0, stream>>>(maskT, f1, f2, WhTf, pnum, pden, HH);
      k_attn_reduce<128, 4><<<HH * NN * 128 / 256, 256, 0, stream>>>(pnum, pden, h0, (long)NN * 128, 128, HH, flag, 0);
      break;
    default:
      k_attn_part<128, 2><<<(NN / 128) * 2 * HH, 256, 0, stream>>>(maskT, f1, f2, WhTf, pnum, pden, HH);
      k_attn_reduce<128, 2><<<HH * NN * 128 / 256, 256, 0, stream>>>(pnum, pden, h0, (long)NN * 128, 128, HH, flag, 0);
  }
  // ---- layer 1 ----
  k_gemm<128, 2, 32><<<dim3(NN / 32, HH), 256, 0, stream>>>(h0, W1T, WhT,
                                                            (long)NN * 128, 128 * 128, (long)128 * NN);
  k_repack<128><<<HH * (NN / 32) * 8 / 4, 256, 0, stream>>>(WhT, WhTf);
  k_f12<128><<<dim3(NN / 256, HH), 256, 0, stream>>>(WhT, a1, flag, f1, f2);
  switch (S) {
    case 8:
      k_attn_part<128, 8><<<(NN / 128) * 8 * HH, 256, 0, stream>>>(maskT, f1, f2, WhTf, pnum, pden, HH);
      k_attn_reduce<128, 8><<<HH * NN * 128 / 256, 256, 0, stream>>>(pnum, pden, hc, 128, 1024, HH, flag, 0);
      break;
    case 4:
      k_attn_part<128, 4><<<(NN / 128) * 4 * HH, 256, 0, stream>>>(maskT, f1, f2, WhTf, pnum, pden, HH);
      k_attn_reduce<128, 4><<<HH * NN * 128 / 256, 256, 0, stream>>>(pnum, pden, hc, 128, 1024, HH, flag, 0);
      break;
    default:
      k_attn_part<128, 2><<<(NN / 128) * 2 * HH, 256, 0, stream>>>(maskT, f1, f2, WhTf, pnum, pden, HH);
      k_attn_reduce<128, 2><<<HH * NN * 128 / 256, 256, 0, stream>>>(pnum, pden, hc, 128, 1024, HH, flag, 0);
  }
  // ---- output layer ----
  k_gemm_out<1024, 4><<<dim3(NN / 16, 4), 256, 0, stream>>>(hc, WoT, gpart);
  k_gemm_red<4><<<64 * NN / 256, 256, 0, stream>>>(gpart, WhoT);
  k_repack<64><<<(NN / 32) * 4 / 4, 256, 0, stream>>>(WhoT, WhoTf);
  k_f12<64><<<dim3(NN / 256, 1), 256, 0, stream>>>(WhoT, ao, flag, fo1, fo2);
  k_attn_part<64, 32><<<(NN / 128) * 32, 256, 0, stream>>>(maskT, fo1, fo2, WhoTf, pnum, pden, 1);
  k_attn_reduce<64, 32><<<NN * 64 / 256, 256, 0, stream>>>(pnum, pden, d_out, 0, 64, 1, flag, 1);
}